// Round 8
// baseline (248.280 us; speedup 1.0000x reference)
//
#include <hip/hip_runtime.h>

// Fully fused: out = wpw · depthwise3x3( bilinear_up(x) )
// x pre-converted to bf16 (d_ws). Tile: 1 out-row x 80 cols x 128 cout.
// 8 K-phases of 32 cin; dbuf bf16 DMA staging; window-gather (2 read2/dy)
// with static 3-coeff taps; 3 blocks/CU; sector-complete NT epilogue.
#define CIN  256
#define HIN  60
#define WIN  80
#define UPH  120
#define UPW  160
#define COUT 128
#define NPIX (UPH*UPW)   // 19200

typedef __bf16 bf16x8 __attribute__((ext_vector_type(8)));
typedef float  floatx4 __attribute__((ext_vector_type(4)));

// ---------------- pre-pass: x fp32 -> bf16 planar (runs once) --------------
__global__ void x_cvt(const float* __restrict__ x, __bf16* __restrict__ xb)
{
    int i = (blockIdx.x * 256 + threadIdx.x) * 8;
    float4 a = *(const float4*)(x + i);
    float4 b = *(const float4*)(x + i + 4);
    bf16x8 o = {(__bf16)a.x,(__bf16)a.y,(__bf16)a.z,(__bf16)a.w,
                (__bf16)b.x,(__bf16)b.y,(__bf16)b.z,(__bf16)b.w};
    *(bf16x8*)(xb + i) = o;
}

#define F_NT 512
#define NPH  8
#define KC   32
#define GPC  19        // granules per ch: 3 rows x 6 + 1 pad (76 dw = 12 mod 32)
#define XFB  10240     // 640 granules x 16B (incl overflow pad)

#define OFF_XF 0       // 2 x 10240 = 20480
#define OFF_DW 20480   // 80 px x 40 sh x 2B = 6400
#define OFF_A  26880   // 256 ch x 12 x 4B = 12288 (end 39168)
#define SMEM_SZ 43008  // epilogue tb = 128 x 84 x 4B

#define FENCE __builtin_amdgcn_sched_barrier(0)

__device__ __forceinline__ float blo(unsigned u){ return __uint_as_float(u << 16); }
__device__ __forceinline__ float bhi(unsigned u){ return __uint_as_float(u & 0xffff0000u); }

__global__ __launch_bounds__(F_NT, 6) void fused_kernel(
    const __bf16* __restrict__ xb16,  // [8,256,60,80] bf16
    const float*  __restrict__ wdw,   // [256,1,3,3]
    const float*  __restrict__ wpw,   // [128,256]
    float* __restrict__ out)          // [8,128,120,160]
{
    __shared__ __align__(16) char smem[SMEM_SZ];
    float*  s_A  = (float*)(smem + OFF_A);
    __bf16* s_dw = (__bf16*)(smem + OFF_DW);

    const int tid = threadIdx.x;

    // XCD-bijective: 1920 = 8 XCDs x 240; XCD k = image k, rows ascend
    const int bid = blockIdx.x;
    const int b   = bid & 7;
    const int r2  = bid >> 3;
    const int h0  = r2 >> 1;
    const int w0  = (r2 & 1) * 80;

    const float HS = 59.0f/121.0f, WS = 79.0f/161.0f;
    const int rbase = (int)((float)h0 * HS);
    const int c0a   = ((int)((float)w0 * WS)) & ~3;   // 0 or 36

    const int lane = tid & 63, wave = tid >> 6;
    const int quad = lane >> 4, l16 = lane & 15;
    const int ch = tid >> 4, seg = tid & 15;          // gather decode

    const __bf16* xb = xb16 + (size_t)b * CIN * (HIN*WIN);

    // ---- row-interp weights (regs) ----
    float rw[9];
    #pragma unroll
    for (int i3 = 0; i3 < 3; ++i3) {
        float hy = (float)(h0 + i3) * HS;
        int y0 = (int)hy; float fy = hy - (float)y0;
        int y1 = min(y0 + 1, HIN - 1);
        #pragma unroll
        for (int dy = 0; dy < 3; ++dy)
            rw[i3*3 + dy] = ((y0 - rbase) == dy ? 1.f - fy : 0.f)
                          + ((y1 - rbase) == dy ? fy : 0.f);
    }

    // ---- wpw A-frag preload (32 VGPR; zero loop vmem) ----
    bf16x8 af[8];
    #pragma unroll
    for (int c = 0; c < 8; ++c) {
        const float* wr = wpw + (size_t)(wave*16 + l16)*CIN + c*KC + quad*8;
        float4 v0 = *(const float4*)wr;
        float4 v1 = *(const float4*)(wr + 4);
        af[c] = (bf16x8){(__bf16)v0.x,(__bf16)v0.y,(__bf16)v0.z,(__bf16)v0.w,
                         (__bf16)v1.x,(__bf16)v1.y,(__bf16)v1.z,(__bf16)v1.w};
    }

    // ---- fold all 256ch A-weights -> s_A[ch][12] (16B-aligned rows) ----
    #pragma unroll
    for (int k = 0; k < 5; ++k) {
        int i = tid + k * F_NT;
        if (i < CIN * 9) {
            int gch = i / 9, t = i - gch * 9;
            int dy = t / 3, j = t - dy * 3;
            const float* wp = wdw + gch*9 + j;
            s_A[gch*12 + t] = rw[dy]*wp[0] + rw[3+dy]*wp[3] + rw[6+dy]*wp[6];
        }
    }

    // ---- per-thread tap coefficients (phase & dy invariant) ----
    // window: bf16 cols [2*D0, 2*D0+8); q[k] = win[p0 + k];
    // tap j: cx = ca*q[g] + cb*q[g+1] + cc*q[g+2], g = {0,0,0,1,1,2,2}
    float ca[7], cbv[7], cc[7];
    int D0; bool p0b;
    {
        const int u0 = w0 + seg * 5;
        float wx0 = (float)u0 * WS;
        int x00 = (int)wx0;
        int ci0 = x00 - c0a;
        D0  = ci0 >> 1;
        p0b = (ci0 & 1) != 0;
        const int gt[7] = {0,0,0,1,1,2,2};
        #pragma unroll
        for (int j = 0; j < 7; ++j) {
            float wx = (float)(u0 + j) * WS;
            int x0 = (int)wx;
            float fxj = wx - (float)x0;
            bool r = (x0 - x00) != gt[j];
            ca[j]  = r ? 0.f        : 1.f - fxj;
            cbv[j] = r ? 1.f - fxj  : fxj;
            cc[j]  = r ? fxj        : 0.f;
        }
    }

    // ---- async DMA: 608 real granules (+32 pad) per phase ----
    auto dma = [&](int cb, char* dst) {
        {   // slot 0: all 8 waves, granules 0..511
            int it = wave*64 + lane;
            int c = it / GPC, t = it - c * GPC;
            int r = t / 6, q = t - r * 6;                 // t=18 -> r=3,q=0 (pad)
            const __bf16* src = xb + ((size_t)(cb + c)*HIN + min(rbase + r, HIN-1))*WIN
                              + c0a + q*8;
            __builtin_amdgcn_global_load_lds(
                (const __attribute__((address_space(1))) void*)src,
                (__attribute__((address_space(3))) void*)(dst + it*16), 16, 0, 0);
        }
        if (wave < 2) {   // slot 1: granules 512..639 (tail + pad)
            int it = 512 + wave*64 + lane;
            int c0 = it / GPC, t = it - c0 * GPC;
            int c = min(c0, KC - 1);
            int r = min(t, 18) / 6, q = min(t, 18) - r * 6;
            const __bf16* src = xb + ((size_t)(cb + c)*HIN + min(rbase + r, HIN-1))*WIN
                              + c0a + q*8;
            __builtin_amdgcn_global_load_lds(
                (const __attribute__((address_space(1))) void*)src,
                (__attribute__((address_space(3))) void*)(dst + it*16), 16, 0, 0);
        }
    };

    floatx4 acc[5];
    #pragma unroll
    for (int n = 0; n < 5; ++n) acc[n] = (floatx4){0.f, 0.f, 0.f, 0.f};

    // prologue: DMA(0) into buf0 (af/wdw loads drained by TOP(0) vmcnt(0))
    dma(0, smem + OFF_XF);

    #pragma unroll
    for (int p = 0; p < NPH; ++p) {
        // TOP: DMA(p) landed; own ds ops drained; barrier (covers s_A on p=0,
        //      MFMA(p-1) b128 reads before s_dw overwrite, buf reads before DMA)
        asm volatile("s_waitcnt vmcnt(0) lgkmcnt(0)" ::: "memory");
        FENCE; __builtin_amdgcn_s_barrier(); FENCE;

        if (p + 1 < NPH) dma((p + 1) * KC, smem + OFF_XF + ((p + 1) & 1) * XFB);

        // ---- window gather + depthwise: 5 px for (ch, seg) ----
        const unsigned* xf = (const unsigned*)(smem + OFF_XF + (p & 1) * XFB);
        const float* Ab = s_A + (p*KC + ch) * 12;
        floatx4 A0 = *(const floatx4*)Ab;         // A[0..3]
        floatx4 A1 = *(const floatx4*)(Ab + 4);   // A[4..7]
        float   A8 = Ab[8];

        float d0 = 0.f, d1 = 0.f, d2 = 0.f, d3 = 0.f, d4 = 0.f;
        #pragma unroll
        for (int dy = 0; dy < 3; ++dy) {
            const unsigned* rp = xf + ch*76 + dy*24 + D0;
            unsigned w0_ = rp[0], w1_ = rp[1], w2_ = rp[2], w3_ = rp[3];
            float f0 = blo(w0_), f1 = bhi(w0_), f2 = blo(w1_), f3 = bhi(w1_);
            float f4 = blo(w2_), f5 = bhi(w2_), f6 = blo(w3_);
            float q0 = p0b ? f1 : f0, q1 = p0b ? f2 : f1, q2 = p0b ? f3 : f2;
            float q3 = p0b ? f4 : f3, q4 = p0b ? f5 : f4;
            float q5_ = p0b ? f6 : f5;  (void)q5_;
            float cx[7];
            cx[0] = ca[0]*q0 + cbv[0]*q1 + cc[0]*q2;
            cx[1] = ca[1]*q0 + cbv[1]*q1 + cc[1]*q2;
            cx[2] = ca[2]*q0 + cbv[2]*q1 + cc[2]*q2;
            cx[3] = ca[3]*q1 + cbv[3]*q2 + cc[3]*q3;
            cx[4] = ca[4]*q1 + cbv[4]*q2 + cc[4]*q3;
            cx[5] = ca[5]*q2 + cbv[5]*q3 + cc[5]*q4;
            cx[6] = ca[6]*q2 + cbv[6]*q3 + cc[6]*q4;
            float t0, t1, t2;
            if (dy == 0)      { t0 = A0[0]; t1 = A0[1]; t2 = A0[2]; }
            else if (dy == 1) { t0 = A0[3]; t1 = A1[0]; t2 = A1[1]; }
            else              { t0 = A1[2]; t1 = A1[3]; t2 = A8;    }
            d0 = fmaf(t0, cx[0], fmaf(t1, cx[1], fmaf(t2, cx[2], d0)));
            d1 = fmaf(t0, cx[1], fmaf(t1, cx[2], fmaf(t2, cx[3], d1)));
            d2 = fmaf(t0, cx[2], fmaf(t1, cx[3], fmaf(t2, cx[4], d2)));
            d3 = fmaf(t0, cx[3], fmaf(t1, cx[4], fmaf(t2, cx[5], d3)));
            d4 = fmaf(t0, cx[4], fmaf(t1, cx[5], fmaf(t2, cx[6], d4)));
        }
        {   // write dw tile [px][k] with quad-group XOR swizzle
            float dd[5] = {d0, d1, d2, d3, d4};
            #pragma unroll
            for (int i = 0; i < 5; ++i) {
                int px = seg*5 + i;
                s_dw[px*40 + (((ch>>3) ^ (px&3))<<3) + (ch&7)] = (__bf16)dd[i];
            }
        }

        // MID: dw tile visible; MFMA (DMA(p+1) stays in flight)
        asm volatile("s_waitcnt lgkmcnt(0)" ::: "memory");
        FENCE; __builtin_amdgcn_s_barrier(); FENCE;

        #pragma unroll
        for (int n = 0; n < 5; ++n) {
            const __bf16* bp = s_dw + (n*16 + l16)*40 + ((quad ^ (l16 & 3)) << 3);
            bf16x8 bfr = *(const bf16x8*)bp;
            acc[n] = __builtin_amdgcn_mfma_f32_16x16x32_bf16(af[p], bfr, acc[n], 0, 0, 0);
        }
    }

    // ---- epilogue: LDS transpose -> sector-complete NT stores ----
    asm volatile("s_waitcnt lgkmcnt(0)" ::: "memory");
    FENCE; __builtin_amdgcn_s_barrier(); FENCE;

    float* tb = (float*)smem;   // [128 cout][84] floats = 43008 B
    #pragma unroll
    for (int n = 0; n < 5; ++n)
        #pragma unroll
        for (int e = 0; e < 4; ++e)
            tb[(wave*16 + quad*4 + e)*84 + n*16 + l16] = acc[n][e];

    asm volatile("s_waitcnt lgkmcnt(0)" ::: "memory");
    FENCE; __builtin_amdgcn_s_barrier(); FENCE;

    const int rr = tid >> 2, sg = tid & 3;
    float* op = out + (size_t)(b*COUT + rr)*NPIX + (size_t)h0*UPW + w0;
    #pragma unroll
    for (int i = 0; i < 5; ++i) {
        int q = i*4 + sg;   // lanes sg=0..3 of instr i cover one 64B sector
        floatx4 v = *(const floatx4*)&tb[rr*84 + q*4];
        __builtin_nontemporal_store(v, (floatx4*)(op + q*4));
    }
}

extern "C" void kernel_launch(void* const* d_in, const int* in_sizes, int n_in,
                              void* d_out, int out_size, void* d_ws, size_t ws_size,
                              hipStream_t stream)
{
    const float* x   = (const float*)d_in[0];
    const float* wdw = (const float*)d_in[1];
    const float* wpw = (const float*)d_in[2];
    __bf16* xb = (__bf16*)d_ws;   // 19.7 MB bf16 copy of x

    x_cvt<<<dim3(4800), 256, 0, stream>>>(x, xb);
    fused_kernel<<<dim3(1920), F_NT, 0, stream>>>(xb, wdw, wpw, (float*)d_out);
}